// Round 5
// baseline (1153.615 us; speedup 1.0000x reference)
//
#include <hip/hip_runtime.h>
#include <hip/hip_fp16.h>
#include <stdint.h>

#define VOCAB 32000
#define EMB   256
#define HID   512
#define BATCH 64
#define SEQ   512

typedef _Float16 f16x8 __attribute__((ext_vector_type(8)));
typedef float    f32x4 __attribute__((ext_vector_type(4)));

__device__ __forceinline__ unsigned int pack2(float x, float y) {
    __half2 h = __floats2half2_rn(x, y);   // v_cvt_pkrtz_f16_f32
    return __builtin_bit_cast(unsigned int, h);
}

// ---------------------------------------------------------------------------
// Kernel 1: pack W_hh (fp32 [m][k]) into per-lane MFMA A-fragments (f16).
// Fragment convention (16x16x32): lane l holds A[m = rt*16 + (l&15)]
// [k = ks*32 + (l>>4)*8 + j], j=0..7 contiguous f16. The same k-order is used
// to build B from h inside the scan, so any hardware k-permutation cancels.
// Tile index tile = ks*4 + rtl (ks 0..15, rtl 0..3), rt = w*4 + rtl.
// Apk layout: [tile*512 + t] uint4, t = w*64 + l  -> scan init loads coalesce.
// ---------------------------------------------------------------------------
__global__ void prep_whh(const float* __restrict__ W_hh, uint4* __restrict__ Apk) {
    int gid = blockIdx.x * blockDim.x + threadIdx.x;
    if (gid >= 64 * 512) return;
    int t    = gid & 511;          // block-thread the fragment belongs to
    int tile = gid >> 9;           // 0..63
    int w = t >> 6, l = t & 63;
    int ks = tile >> 2, rtl = tile & 3;
    int m  = (w * 4 + rtl) * 16 + (l & 15);
    int kb = ks * 32 + (l >> 4) * 8;
    const float* src = W_hh + (size_t)m * HID + kb;
    float4 v0 = *(const float4*)(src);
    float4 v1 = *(const float4*)(src + 4);
    uint4 o;
    o.x = pack2(v0.x, v0.y);
    o.y = pack2(v0.z, v0.w);
    o.z = pack2(v1.x, v1.y);
    o.w = pack2(v1.z, v1.w);
    Apk[(size_t)tile * 512 + t] = o;
}

// ---------------------------------------------------------------------------
// Kernel 2: xin[b][s][h] = emb[X[b][s]] . W_ih[h] + b_ih[h] + b_hh[h]  (fp16 out)
// 128x128 tile, BK=32, 256 thr, 8x8 fp32 acc/thread.
// PRECISION (round-4 lesson): inputs MUST stay fp32 — the recurrence amplifies
// xin error (||W_hh||_2 ~ 2.3 pre-saturation); fp16 inputs failed absmax
// (0.121 > 0.0775). Only the OUTPUT is rounded to fp16 (baseline-proven).
// ---------------------------------------------------------------------------
#define TSA 132

__global__ __launch_bounds__(256) void embed_gemm(
    const int* __restrict__ X, const float* __restrict__ emb,
    const float* __restrict__ W_ih, const float* __restrict__ b_ih,
    const float* __restrict__ b_hh, __half* __restrict__ xin) {
    __shared__ float A_l[32 * TSA];
    __shared__ float B_l[32 * TSA];
    const int tid = threadIdx.x;
    const int tx = tid & 15, ty = tid >> 4;
    const int sb0 = blockIdx.x * 128;   // (b*S+s) row tile
    const int h0  = blockIdx.y * 128;   // hidden col tile

    float acc[8][8] = {};

    for (int kc = 0; kc < EMB; kc += 32) {
#pragma unroll
        for (int q = 0; q < 4; ++q) {
            int idx = q * 256 + tid;
            int r  = idx >> 3;
            int c4 = idx & 7;
            int row = X[sb0 + r];
            float4 v = *(const float4*)(emb + (size_t)row * EMB + kc + c4 * 4);
            A_l[(c4 * 4 + 0) * TSA + r] = v.x;
            A_l[(c4 * 4 + 1) * TSA + r] = v.y;
            A_l[(c4 * 4 + 2) * TSA + r] = v.z;
            A_l[(c4 * 4 + 3) * TSA + r] = v.w;
        }
#pragma unroll
        for (int q = 0; q < 4; ++q) {
            int idx = q * 256 + tid;
            int r  = idx >> 3;
            int c4 = idx & 7;
            float4 v = *(const float4*)(W_ih + (size_t)(h0 + r) * EMB + kc + c4 * 4);
            B_l[(c4 * 4 + 0) * TSA + r] = v.x;
            B_l[(c4 * 4 + 1) * TSA + r] = v.y;
            B_l[(c4 * 4 + 2) * TSA + r] = v.z;
            B_l[(c4 * 4 + 3) * TSA + r] = v.w;
        }
        __syncthreads();
#pragma unroll
        for (int k = 0; k < 32; ++k) {
            float4 a0 = *(const float4*)&A_l[k * TSA + ty * 4];
            float4 a1 = *(const float4*)&A_l[k * TSA + 64 + ty * 4];
            float4 b0 = *(const float4*)&B_l[k * TSA + tx * 4];
            float4 b1 = *(const float4*)&B_l[k * TSA + 64 + tx * 4];
            float ar[8] = {a0.x, a0.y, a0.z, a0.w, a1.x, a1.y, a1.z, a1.w};
            float br[8] = {b0.x, b0.y, b0.z, b0.w, b1.x, b1.y, b1.z, b1.w};
#pragma unroll
            for (int i = 0; i < 8; ++i)
#pragma unroll
                for (int j = 0; j < 8; ++j)
                    acc[i][j] = fmaf(ar[i], br[j], acc[i][j]);
        }
        __syncthreads();
    }

    float bias[8];
#pragma unroll
    for (int j = 0; j < 8; ++j) {
        int h = h0 + (j < 4 ? tx * 4 + j : 64 + tx * 4 + (j - 4));
        bias[j] = b_ih[h] + b_hh[h];
    }
#pragma unroll
    for (int i = 0; i < 8; ++i) {
        int r = sb0 + (i < 4 ? ty * 4 + i : 64 + ty * 4 + (i - 4));
        __half* dst = xin + (size_t)r * HID + h0;
        __half2 v01 = __floats2half2_rn(acc[i][0] + bias[0], acc[i][1] + bias[1]);
        __half2 v23 = __floats2half2_rn(acc[i][2] + bias[2], acc[i][3] + bias[3]);
        __half2 v45 = __floats2half2_rn(acc[i][4] + bias[4], acc[i][5] + bias[5]);
        __half2 v67 = __floats2half2_rn(acc[i][6] + bias[6], acc[i][7] + bias[7]);
        *(__half2*)(dst + tx * 4)          = v01;
        *(__half2*)(dst + tx * 4 + 2)      = v23;
        *(__half2*)(dst + 64 + tx * 4)     = v45;
        *(__half2*)(dst + 64 + tx * 4 + 2) = v67;
    }
}

// ---------------------------------------------------------------------------
// Kernel 3: sequential RNN scan via MFMA. One 512-thread block per batch chain.
// ROUND-5 REWRITE: rounds 0-3 proved weights park in AGPRs (128 arch + 128 AGPR
// split at 2 waves/SIMD is immovable) and v_dot2 can't source AGPRs -> ~130
// v_accvgpr_read copies/thread/step. v_mfma_f32_16x16x32_f16 CAN source AGPRs
// directly -> copies gone, matrix pipe does the matvec.
//   - Per wave: 4 row-tiles (rt = w*4+rtl, rows w*64..w*64+63) x 16 k-slices.
//     B = [h-slice | 0..0] (col 0 only): 64 MFMA/wave/step, fp32 accumulate.
//   - Weights: 48 tiles in RF (192 dw, AGPR-parked is fine) + 16 tail tiles in
//     LDS wt (stride 17*uint4 = 68 dw == 4 mod 32 -> b128 conflict-free).
//   - B-build: lanes with (l&15)==0 read h[ks*32 + (l>>4)*8 ..+7] (b128 from
//     hbuf); other 60 lanes read a zero pad at stride 0 (broadcast, free).
//     Same k-order as the A-pack -> hardware k-permutation cancels.
//   - D (m89-verified: col=lane&15, row=(lane>>4)*4+reg): col-0 lanes scatter
//     16 f32 each into dred[row]; barrier; every lane does tanh for its own
//     row -> coalesced global I/O identical to the old kernel.
//   - Numerics unchanged vs fdot2 path: f16 W, f16 h, fp32 accumulate.
// ---------------------------------------------------------------------------
#define NRF 48                 // A tiles in registers (ks 0..11)
#define NLT 16                 // A tiles in LDS      (ks 12..15)

__global__
__attribute__((amdgpu_flat_work_group_size(512, 512), amdgpu_waves_per_eu(2, 2)))
void rnn_scan(
    __half* __restrict__ buf,                 // [B][S][HID] fp16: xin in, h out
    const uint4* __restrict__ Apk) {
    __shared__ uint4  wt[512 * 17];           // 139,264 B: tail A tiles
    __shared__ __half hbuf[2][HID];           // 2 KB: h double buffer
    __shared__ float  dred[HID];              // 2 KB: D redistribution
    __shared__ float  zp[4];                  // 16 B zeros (inactive B lanes)

    const int t = threadIdx.x;
    const int b = blockIdx.x;
    const int l = t & 63;
    const int w = t >> 6;
    const int q = l >> 4;                     // 0..3
    const bool act = (l & 15) == 0;

    // --- init: load A fragments (coalesced: consecutive t -> consecutive uint4)
    f16x8 wreg[NRF];
#pragma unroll
    for (int i = 0; i < NRF; ++i)
        wreg[i] = __builtin_bit_cast(f16x8, Apk[(size_t)i * 512 + t]);
#pragma unroll
    for (int i = 0; i < NLT; ++i)
        wt[t * 17 + i] = Apk[(size_t)(NRF + i) * 512 + t];
    for (int i = t; i < 2 * HID; i += 512) ((__half*)hbuf)[i] = __float2half(0.0f);
    if (t < 4) zp[t] = 0.0f;
    __syncthreads();

    const __half* xp = buf + (size_t)b * SEQ * HID + t;   // this thread's row
    __half*       op = buf + (size_t)b * SEQ * HID + t;

    float xcur = __half2float(xp[0]);
    __half hprev = __float2half(0.0f);

    const char* hb_base = (const char*)hbuf;
    const char* zpp     = (const char*)zp;
    const int   bstride = act ? 64 : 0;       // bytes per k-slice step (0 = stay on zeros)

    for (int s = 0; s < SEQ; ++s) {
        if (s > 0) op[(size_t)(s - 1) * HID] = hprev;     // write h(s-1), coalesced
        float xnext = 0.0f;
        if (s + 1 < SEQ) xnext = __half2float(xp[(size_t)(s + 1) * HID]);

        const char* bp = act ? (hb_base + (s & 1) * (HID * 2) + q * 16) : zpp;

        f32x4 acc[4] = {};
#pragma unroll
        for (int ks = 0; ks < 12; ++ks) {                 // RF-resident A tiles
            f16x8 bf = *(const f16x8*)bp;
            bp += bstride;
#pragma unroll
            for (int rtl = 0; rtl < 4; ++rtl)
                acc[rtl] = __builtin_amdgcn_mfma_f32_16x16x32_f16(
                    wreg[ks * 4 + rtl], bf, acc[rtl], 0, 0, 0);
        }
#pragma unroll
        for (int ks = 12; ks < 16; ++ks) {                // LDS-resident A tiles
            f16x8 bf = *(const f16x8*)bp;
            bp += bstride;
#pragma unroll
            for (int rtl = 0; rtl < 4; ++rtl) {
                f16x8 af = __builtin_bit_cast(f16x8, wt[t * 17 + (ks - 12) * 4 + rtl]);
                acc[rtl] = __builtin_amdgcn_mfma_f32_16x16x32_f16(
                    af, bf, acc[rtl], 0, 0, 0);
            }
        }

        // scatter D col 0 -> dred[row]; row = w*64 + rtl*16 + q*4 + reg
        if (act) {
#pragma unroll
            for (int rtl = 0; rtl < 4; ++rtl)
                *(f32x4*)&dred[w * 64 + rtl * 16 + q * 4] = acc[rtl];
        }
        __syncthreads();                                  // barrier 1: dred ready

        float z = xcur + dred[t];
        float e = __expf(2.0f * z);                       // tanh via exp
        float hn = 1.0f - 2.0f / (e + 1.0f);
        __half hh = __float2half(hn);
        hbuf[(s + 1) & 1][t] = hh;
        hprev = hh;
        xcur = xnext;
        __syncthreads();                                  // barrier 2: h(next) ready
    }
    op[(size_t)(SEQ - 1) * HID] = hprev;
}

// ---------------------------------------------------------------------------
// Kernel 4: attention over trajectory + feat assembly. One block per batch.
// ---------------------------------------------------------------------------
__global__ __launch_bounds__(256) void attn_ctx(
    const __half* __restrict__ h_all, float* __restrict__ feat) {
    const int b = blockIdx.x, tid = threadIdx.x;
    __shared__ float lastv[HID];
    __shared__ float sc[SEQ];
    __shared__ float red[256];
    const __half* hb = h_all + (size_t)b * SEQ * HID;

    for (int i = tid; i < HID; i += 256)
        lastv[i] = __half2float(hb[(size_t)(SEQ - 1) * HID + i]);
    __syncthreads();

    for (int s = tid; s < SEQ - 1; s += 256) {
        const __half* row = hb + (size_t)s * HID;
        float acc = 0.f;
        for (int r = 0; r < HID; r += 2) {
            __half2 hv = *(const __half2*)(row + r);
            float2 f = __half22float2(hv);
            acc = fmaf(f.x, lastv[r], acc);
            acc = fmaf(f.y, lastv[r + 1], acc);
        }
        sc[s] = acc;
    }
    __syncthreads();

    float m = -1e30f;
    for (int s = tid; s < SEQ - 1; s += 256) m = fmaxf(m, sc[s]);
    red[tid] = m;
    __syncthreads();
    for (int o = 128; o > 0; o >>= 1) {
        if (tid < o) red[tid] = fmaxf(red[tid], red[tid + o]);
        __syncthreads();
    }
    m = red[0];
    __syncthreads();

    float psum = 0.f;
    for (int s = tid; s < SEQ - 1; s += 256) {
        float e = expf(sc[s] - m);
        sc[s] = e;
        psum += e;
    }
    red[tid] = psum;
    __syncthreads();
    for (int o = 128; o > 0; o >>= 1) {
        if (tid < o) red[tid] += red[tid + o];
        __syncthreads();
    }
    float inv = 1.0f / red[0];
    __syncthreads();

    for (int r2 = tid; r2 < HID / 2; r2 += 256) {
        int r = r2 * 2;
        float accx = 0.f, accy = 0.f;
        int s = 0;
        for (; s + 4 <= SEQ - 1; s += 4) {
#pragma unroll
            for (int u = 0; u < 4; ++u) {
                __half2 hv = *(const __half2*)(hb + (size_t)(s + u) * HID + r);
                float2 f = __half22float2(hv);
                float w = sc[s + u];
                accx = fmaf(w, f.x, accx);
                accy = fmaf(w, f.y, accy);
            }
        }
        for (; s < SEQ - 1; ++s) {
            __half2 hv = *(const __half2*)(hb + (size_t)s * HID + r);
            float2 f = __half22float2(hv);
            float w = sc[s];
            accx = fmaf(w, f.x, accx);
            accy = fmaf(w, f.y, accy);
        }
        feat[(size_t)b * 2 * HID + r]     = accx * inv;
        feat[(size_t)b * 2 * HID + r + 1] = accy * inv;
        feat[(size_t)b * 2 * HID + HID + r]     = lastv[r];
        feat[(size_t)b * 2 * HID + HID + r + 1] = lastv[r + 1];
    }
}

// ---------------------------------------------------------------------------
// Kernel 5: out[b][v] = feat[b] . W[v] + bias[v].  64 v-rows x 64 b per block.
// ---------------------------------------------------------------------------
#define TS 68

__global__ __launch_bounds__(256) void final_gemm(
    const float* __restrict__ W, const float* __restrict__ bias,
    const float* __restrict__ feat, float* __restrict__ out) {
    __shared__ float A_l[64 * TS];   // W tile, k-major
    __shared__ float B_l[64 * TS];   // feat tile, k-major
    const int tid = threadIdx.x;
    const int tx = tid & 15, ty = tid >> 4;
    const int v0 = blockIdx.x * 64;

    float acc[4][4] = {};

    for (int kc = 0; kc < 2 * HID; kc += 64) {
#pragma unroll
        for (int q = 0; q < 4; ++q) {
            int idx = q * 256 + tid;
            int r  = idx >> 4;
            int c4 = idx & 15;
            const float4 v = *(const float4*)(W + (size_t)(v0 + r) * (2 * HID) + kc + c4 * 4);
            A_l[(c4 * 4 + 0) * TS + r] = v.x;
            A_l[(c4 * 4 + 1) * TS + r] = v.y;
            A_l[(c4 * 4 + 2) * TS + r] = v.z;
            A_l[(c4 * 4 + 3) * TS + r] = v.w;
        }
#pragma unroll
        for (int q = 0; q < 4; ++q) {
            int idx = q * 256 + tid;
            int r  = idx >> 4;
            int c4 = idx & 15;
            const float4 v = *(const float4*)(feat + (size_t)r * (2 * HID) + kc + c4 * 4);
            B_l[(c4 * 4 + 0) * TS + r] = v.x;
            B_l[(c4 * 4 + 1) * TS + r] = v.y;
            B_l[(c4 * 4 + 2) * TS + r] = v.z;
            B_l[(c4 * 4 + 3) * TS + r] = v.w;
        }
        __syncthreads();
#pragma unroll 8
        for (int k = 0; k < 64; ++k) {
            float4 av = *(const float4*)&A_l[k * TS + ty * 4];
            float4 bv = *(const float4*)&B_l[k * TS + tx * 4];
            float a[4] = {av.x, av.y, av.z, av.w};
            float bb[4] = {bv.x, bv.y, bv.z, bv.w};
#pragma unroll
            for (int i = 0; i < 4; ++i)
#pragma unroll
                for (int ii = 0; ii < 4; ++ii)
                    acc[i][ii] = fmaf(a[i], bb[ii], acc[i][ii]);
        }
        __syncthreads();
    }

    float bs[4];
#pragma unroll
    for (int i = 0; i < 4; ++i) bs[i] = bias[v0 + ty * 4 + i];
#pragma unroll
    for (int ii = 0; ii < 4; ++ii) {
        int bb = tx * 4 + ii;
        float4 o;
        o.x = acc[0][ii] + bs[0];
        o.y = acc[1][ii] + bs[1];
        o.z = acc[2][ii] + bs[2];
        o.w = acc[3][ii] + bs[3];
        *(float4*)(out + (size_t)bb * VOCAB + v0 + ty * 4) = o;
    }
}

// ---------------------------------------------------------------------------
extern "C" void kernel_launch(void* const* d_in, const int* in_sizes, int n_in,
                              void* d_out, int out_size, void* d_ws, size_t ws_size,
                              hipStream_t stream) {
    const int*   X    = (const int*)d_in[0];
    const float* emb  = (const float*)d_in[1];
    const float* W_ih = (const float*)d_in[2];
    const float* W_hh = (const float*)d_in[3];
    const float* b_ih = (const float*)d_in[4];
    const float* b_hh = (const float*)d_in[5];
    const float* W    = (const float*)d_in[6];
    const float* bias = (const float*)d_in[7];
    float* out = (float*)d_out;

    // workspace: buf (xin fp16, overlaid with h) 32 MB | Apk 512 KB | feat 256 KB
    const size_t BUF_B  = (size_t)BATCH * SEQ * HID * sizeof(__half);  // 33554432
    const size_t APK_B  = (size_t)64 * 512 * sizeof(uint4);            //   524288
    const size_t FEAT_B = (size_t)BATCH * 2 * HID * sizeof(float);     //   262144
    if (ws_size < BUF_B + APK_B + FEAT_B) return;  // fail clean, don't corrupt

    char* ws = (char*)d_ws;
    __half* buf  = (__half*)ws;
    uint4*  Apk  = (uint4*)(ws + BUF_B);
    float*  feat = (float*)(ws + BUF_B + APK_B);

    prep_whh<<<(64 * 512 + 255) / 256, 256, 0, stream>>>(W_hh, Apk);
    embed_gemm<<<dim3(BATCH * SEQ / 128, HID / 128), 256, 0, stream>>>(
        X, emb, W_ih, b_ih, b_hh, buf);
    rnn_scan<<<BATCH, 512, 0, stream>>>(buf, Apk);
    attn_ctx<<<BATCH, 256, 0, stream>>>(buf, feat);
    final_gemm<<<VOCAB / 64, 256, 0, stream>>>(W, bias, feat, out);
}